// Round 5
// baseline (25.136 us; speedup 1.0000x reference)
//
#include <hip/hip_runtime.h>
#include <float.h>

// ROI adaptive max pool 7x7 over top-left h[n] x w[n] region of 14x14 planes.
// N=512, C=256, HMAX=WMAX=14, OUT=7. Bin spans are 1..3 per dim.
//
// Round-4 lesson: 9x ds_read_b32 scatter per output left the LDS pipe at
// ~44 B/cyc (~14us/CU) alongside a ~16us memory floor. This version:
//  - stages rows 0..Lh-1 of 16 planes via coalesced float4 (row-skip kept),
//  - one thread per (plane, out-row): reads 3 source rows as float2 (b64),
//    vertical max into vm[14] registers,
//  - horizontal 7-bin max fully in registers; column indices depend only on
//    block-uniform Lw -> scalar switch to template<int LW> body so all vm[]
//    indices are compile-time (no scratch spill),
//  - outputs staged in LDS, written back as coalesced float4.

constexpr int N_   = 512;
constexpr int C_   = 256;
constexpr int WMAX = 14;
constexpr int OUT  = 7;
constexpr int PLANE = 196;                      // 14*14 floats
constexpr int P     = 16;                       // planes per block
constexpr int NBLK  = (N_ * C_) / P;            // 8192 blocks
constexpr int NOUT  = P * OUT * OUT;            // 784 outputs per block

template<int LW>
__device__ __forceinline__ void hpool(const float (&vm)[WMAX], float (&o)[OUT]) {
    #pragma unroll
    for (int j = 0; j < OUT; ++j) {
        // compile-time bin columns (j unrolled, LW template param)
        int c1 = (j * LW) / 7;
        int c3 = ((j + 1) * LW + 6) / 7 - 1;
        int c2 = (c1 + 1 < c3) ? c1 + 1 : c3;
        o[j] = fmaxf(fmaxf(vm[c1], vm[c2]), vm[c3]);
    }
}

__global__ __launch_bounds__(256) void roipool_kernel(
    const float* __restrict__ rois,
    const int*   __restrict__ h,
    const int*   __restrict__ w,
    float*       __restrict__ out)
{
    __shared__ float lds[P * PLANE];            // 12544 B
    __shared__ float ostage[NOUT];              // 3136 B

    const int tid = threadIdx.x;
    const int blk = blockIdx.x;

    // block-uniform ROI size (16 blocks per image -> scalar loads)
    const int n  = blk >> 4;
    const int Lh = h[n];
    const int Lw = w[n];
    const int V  = (7 * Lh + 1) >> 1;           // float4s per plane covering rows < Lh

    // ---- stage: 16 threads per plane, float4, rows >= Lh skipped ----
    {
        const float4* src = (const float4*)rois + (size_t)blk * (NOUT);
        float4* ldsv = (float4*)lds;
        int p = tid >> 4;
        int l = tid & 15;
        int base = p * 49;                      // plane stride = 49 float4
        for (int v = l; v < V; v += 16)
            ldsv[base + v] = src[base + v];
    }
    __syncthreads();

    // ---- compute: one thread per (plane, out-row): 112 threads ----
    if (tid < P * OUT) {
        int p = tid / 7;
        int i = tid - p * 7;

        int th = i * Lh;
        int r1 = th / 7;
        int r3 = (th + Lh + 6) / 7 - 1;         // ceil((i+1)Lh/7)-1
        int r2 = min(r1 + 1, r3);

        const float2* a = (const float2*)(lds + p * PLANE + r1 * WMAX);
        const float2* b = (const float2*)(lds + p * PLANE + r2 * WMAX);
        const float2* c = (const float2*)(lds + p * PLANE + r3 * WMAX);

        float vm[WMAX];
        #pragma unroll
        for (int k = 0; k < 7; ++k) {
            float2 x = a[k], y = b[k], z = c[k];
            vm[2 * k]     = fmaxf(fmaxf(x.x, y.x), z.x);
            vm[2 * k + 1] = fmaxf(fmaxf(x.y, y.y), z.y);
        }

        float o[OUT];
        switch (Lw) {                           // block-uniform -> scalar branch
            case  7: hpool< 7>(vm, o); break;
            case  8: hpool< 8>(vm, o); break;
            case  9: hpool< 9>(vm, o); break;
            case 10: hpool<10>(vm, o); break;
            case 11: hpool<11>(vm, o); break;
            case 12: hpool<12>(vm, o); break;
            case 13: hpool<13>(vm, o); break;
            default: hpool<14>(vm, o); break;
        }

        float* os = ostage + tid * OUT;
        #pragma unroll
        for (int j = 0; j < OUT; ++j) os[j] = o[j];
    }
    __syncthreads();

    // ---- write back: coalesced float4 ----
    if (tid < NOUT / 4) {
        float4 v = ((const float4*)ostage)[tid];
        ((float4*)out)[(size_t)blk * (NOUT / 4) + tid] = v;
    }
}

extern "C" void kernel_launch(void* const* d_in, const int* in_sizes, int n_in,
                              void* d_out, int out_size, void* d_ws, size_t ws_size,
                              hipStream_t stream)
{
    const float* rois = (const float*)d_in[0];
    const int*   h    = (const int*)d_in[1];
    const int*   w    = (const int*)d_in[2];
    float*       out  = (float*)d_out;

    roipool_kernel<<<NBLK, 256, 0, stream>>>(rois, h, w, out);
}

// Round 6
// 24.457 us; speedup vs baseline: 1.0277x; 1.0277x over previous
//
#include <hip/hip_runtime.h>

// ROI adaptive max pool 7x7 over top-left h[n] x w[n] of 14x14 planes.
// N=512, C=256. Bin spans 1..3 per dim -> branchless 3-point max per dim.
//
// Round-6 structure: persistent pipelined blocks (T3-lite).
//  - G=1024 blocks x T=8 tiles (16 planes each), all blocks resident.
//  - Staging via global_load_lds width=16: one exec-masked load per plane
//    (lanes 0..V-1, V = float4s covering rows < Lh -> row-skip kept).
//  - Double-buffered LDS, RAW s_barrier + counted vmcnt (never vmcnt(0) in
//    the loop) so next tile's loads stay in flight across barriers.
//  - Plane stride 65 float4: masked-lane LDS slots are padding (safe either
//    way), and 260 floats % 32 banks = 4 keeps compute reads staggered.
//  - Compute: 112 threads, float2 row reads, vertical max in regs,
//    horizontal bins via template<LW> (block-uniform switch), ostage + f4 out.

constexpr int N_    = 512;
constexpr int C_    = 256;
constexpr int WMAX  = 14;
constexpr int OUT   = 7;
constexpr int P     = 16;                 // planes per tile
constexpr int NTILE = (N_ * C_) / P;      // 8192
constexpr int G     = 1024;               // blocks (4/CU, all resident)
constexpr int T     = NTILE / G;          // 8 tiles per block
constexpr int PS4   = 65;                 // LDS plane stride in float4 (padded)
constexpr int PSF   = PS4 * 4;            // 260 floats
constexpr int NOUT  = P * OUT * OUT;      // 784 outputs per tile

typedef const __attribute__((address_space(1))) unsigned int* gas_u32;
typedef __attribute__((address_space(3))) unsigned int* las_u32;

template<int LW>
__device__ __forceinline__ void hpool(const float (&vm)[WMAX], float (&o)[OUT]) {
    #pragma unroll
    for (int j = 0; j < OUT; ++j) {
        int c1 = (j * LW) / 7;
        int c3 = ((j + 1) * LW + 6) / 7 - 1;
        int c2 = (c1 + 1 < c3) ? c1 + 1 : c3;
        o[j] = fmaxf(fmaxf(vm[c1], vm[c2]), vm[c3]);
    }
}

__global__ __launch_bounds__(256) void roipool_kernel(
    const float* __restrict__ rois,
    const int*   __restrict__ h,
    const int*   __restrict__ w,
    float*       __restrict__ out)
{
    __shared__ float4 buf[2][P * PS4];    // 2 x 16640 B
    __shared__ float  ostage[NOUT];       // 3136 B

    const int tid  = threadIdx.x;
    const int lane = tid & 63;
    const int wv   = tid >> 6;
    const int blk  = blockIdx.x;

    // prefetch all tile ROI sizes (block-uniform -> scalar loads)
    int LH[T], LWv[T];
    #pragma unroll
    for (int k = 0; k < T; ++k) {
        int n = (blk >> 4) + 64 * k;      // (blk + k*G) / 16
        LH[k]  = h[n];
        LWv[k] = w[n];
    }

    auto stage = [&](int k, int b) {
        const float4* src = (const float4*)rois + (size_t)(blk + k * G) * (P * 49);
        const int V = (7 * LH[k] + 1) >> 1;       // float4s covering rows < Lh (25..49)
        #pragma unroll
        for (int s = 0; s < 4; ++s) {
            const int p  = 4 * wv + s;
            const int l2 = (lane < V) ? lane : 0; // clamp masked-lane addresses
            if (lane < V) {
                __builtin_amdgcn_global_load_lds(
                    (gas_u32)(src + p * 49 + l2),
                    (las_u32)(&buf[b][p * PS4]),
                    16, 0, 0);
            }
        }
    };

    stage(0, 0);

    #pragma unroll
    for (int t = 0; t < T; ++t) {
        if (t + 1 < T) stage(t + 1, (t + 1) & 1);

        // wait for tile t's 4 staging loads; keep tile t+1's in flight.
        // newer-than-stage(t): t==0 -> stage(1)x4 = 4; middle -> +store(t-1) = 5;
        // last -> store(t-1) only = 1.
        if (t == 0)          asm volatile("s_waitcnt vmcnt(4)" ::: "memory");
        else if (t == T - 1) asm volatile("s_waitcnt vmcnt(1)" ::: "memory");
        else                 asm volatile("s_waitcnt vmcnt(5)" ::: "memory");
        __builtin_amdgcn_s_barrier();
        asm volatile("" ::: "memory");    // keep LDS reads below the barrier

        if (tid < P * OUT) {              // 112 threads: one (plane, out-row) each
            const int p  = tid / 7;
            const int i  = tid - p * 7;
            const int Lh = LH[t];

            int th = i * Lh;
            int r1 = th / 7;
            int r3 = (th + Lh + 6) / 7 - 1;
            int r2 = min(r1 + 1, r3);

            const float*  pb = (const float*)&buf[t & 1][0] + p * PSF;
            const float2* a  = (const float2*)(pb + r1 * WMAX);
            const float2* bb = (const float2*)(pb + r2 * WMAX);
            const float2* c  = (const float2*)(pb + r3 * WMAX);

            float vm[WMAX];
            #pragma unroll
            for (int kk = 0; kk < 7; ++kk) {
                float2 x = a[kk], y = bb[kk], z = c[kk];
                vm[2 * kk]     = fmaxf(fmaxf(x.x, y.x), z.x);
                vm[2 * kk + 1] = fmaxf(fmaxf(x.y, y.y), z.y);
            }

            float o[OUT];
            switch (LWv[t]) {
                case  7: hpool< 7>(vm, o); break;
                case  8: hpool< 8>(vm, o); break;
                case  9: hpool< 9>(vm, o); break;
                case 10: hpool<10>(vm, o); break;
                case 11: hpool<11>(vm, o); break;
                case 12: hpool<12>(vm, o); break;
                case 13: hpool<13>(vm, o); break;
                default: hpool<14>(vm, o); break;
            }

            float* os = ostage + tid * OUT;
            #pragma unroll
            for (int j = 0; j < OUT; ++j) os[j] = o[j];
        }

        asm volatile("s_waitcnt lgkmcnt(0)" ::: "memory");
        __builtin_amdgcn_s_barrier();
        asm volatile("" ::: "memory");    // keep ostage reads below the barrier

        if (tid < NOUT / 4) {             // coalesced float4 writeback
            ((float4*)out)[(size_t)(blk + t * G) * (NOUT / 4) + tid] =
                ((const float4*)ostage)[tid];
        }
        // buf[(t+1)&1] safety: compute(t) LDS reads completed before the
        // lgkmcnt(0)+barrier above; stage(t+2) (which reuses buf[t&1]) is
        // issued only after that barrier next iteration.
    }
}

extern "C" void kernel_launch(void* const* d_in, const int* in_sizes, int n_in,
                              void* d_out, int out_size, void* d_ws, size_t ws_size,
                              hipStream_t stream)
{
    const float* rois = (const float*)d_in[0];
    const int*   h    = (const int*)d_in[1];
    const int*   w    = (const int*)d_in[2];
    float*       out  = (float*)d_out;

    roipool_kernel<<<G, 256, 0, stream>>>(rois, h, w, out);
}